// Round 1
// baseline (478.387 us; speedup 1.0000x reference)
//
#include <hip/hip_runtime.h>
#include <math.h>

// ---------------------------------------------------------------------------
// EquivariantMPBlock, round 6.
//   phase1 feat: ONE WAVE PER NODE, barrier-free. Stage 512B via float2 load +
//     ds_write_b64 into a per-wave LDS slice; read back as 40x ds_read_b128
//     broadcasts (was 160x ds_read_b32 + 2 barriers/node). hv lanes compute all
//     3 d-components of their channel (v elems 3k+d are contiguous -> full
//     density from float4 reads, compile-time k/d extraction). Coalesced
//     ushort4 feat stores (sc via one __shfl).
//   phase1 scatter: THIN 4B payload (col only) - removes 24 pos gathers/quad
//     and quarters scattered-write footprint. 4 independent atomic chains.
//   agg: geometry inline (row pos once per node; col pos as 3 broadcast loads
//     per edge), two-phase unrolled 8/4/1 edge chunks for gather ILP.
// ---------------------------------------------------------------------------

static constexpr float INV_SQRT_MUL = 0.17677669529663687f;   // 1/sqrt(32)
static constexpr float C_DOT = 0.10206207261596575f;          // 1/sqrt(96)
static constexpr float C_SCL = 0.07216878364870322f;          // 1/sqrt(192)
static constexpr float C_CRS = 0.05103103630798288f;          // 1/sqrt(384)
static constexpr float SQRT3 = 1.7320508075688772f;
static constexpr int MAXDEG = 48;
static constexpr int SCAT_B = 1024;   // scatter blocks (scheduled first)
static constexpr int FEAT_B = 1024;   // feat blocks (4 independent waves each)

#define WS_ALIGN(x) (((x) + 255) & ~(size_t)255)

__device__ __forceinline__ unsigned short f2bf(float v) {
    unsigned int b = __float_as_uint(v);
    b += 0x7FFFu + ((b >> 16) & 1u);   // RNE
    return (unsigned short)(b >> 16);
}
__device__ __forceinline__ float bf2f(unsigned short u) {
    return __uint_as_float(((unsigned int)u) << 16);
}

// --- fused + pre-scaled weights into contiguous Wall[3072]; zero cnt ---------
__global__ __launch_bounds__(1024)
void fuse_zero(const float* __restrict__ Wtpd, const float* __restrict__ Wtps,
               const float* __restrict__ Wtpc, const float* __restrict__ Wms,
               const float* __restrict__ Wmv, float* __restrict__ Wall,
               int* __restrict__ cnt, int N) {
    int t = threadIdx.x;
    if (blockIdx.x == 0) {
        int i = t >> 5, j = t & 31;
        float a = 0.f, b = 0.f, c = 0.f;
#pragma unroll
        for (int k = 0; k < 32; ++k) {
            a += Wtpd[i * 32 + k] * Wms[k * 32 + j];
            b += Wtps[i * 32 + k] * Wmv[k * 32 + j];
            c += Wtpc[i * 32 + k] * Wmv[k * 32 + j];
        }
        Wall[t]        = a * (C_DOT * INV_SQRT_MUL);
        Wall[1024 + t] = b * (C_SCL * INV_SQRT_MUL);
        Wall[2048 + t] = c * (C_CRS * INV_SQRT_MUL);
    } else {
        int i = (blockIdx.x - 1) * 1024 + t;
        if (i < N) cnt[i] = 0;
    }
}

// --- phase1: scatter blocks [0,SCAT_B) + feat blocks [SCAT_B, SCAT_B+FEAT_B) -
__global__ __launch_bounds__(256)
void phase1(const float* __restrict__ x, const float* __restrict__ Wns,
            const float* __restrict__ Wnv, const int* __restrict__ eidx,
            ushort4* __restrict__ feat4, int* __restrict__ cnt,
            int* __restrict__ slots, int N, int E) {
    __shared__ float xs[4 * 128];          // 512B per wave, wave-private
    int t = threadIdx.x;
    if (blockIdx.x < SCAT_B) {
        // ---- edge scatter: thin 4B payload, int4-vectorized, 4 MLP chains ---
        int tid = blockIdx.x * 256 + t;
        int Q = E >> 2;
        const int4* r4p = (const int4*)eidx;
        const int4* c4p = (const int4*)(eidx + E);
        for (int q = tid; q < Q; q += SCAT_B * 256) {
            int4 R = r4p[q];
            int4 C = c4p[q];
            int rr[4] = {R.x, R.y, R.z, R.w};
            int cc[4] = {C.x, C.y, C.z, C.w};
            int p[4];
#pragma unroll
            for (int k = 0; k < 4; ++k) p[k] = atomicAdd(&cnt[rr[k]], 1);
#pragma unroll
            for (int k = 0; k < 4; ++k)
                if (p[k] < MAXDEG) slots[(size_t)rr[k] * MAXDEG + p[k]] = cc[k];
        }
        for (int e = (Q << 2) + tid; e < E; e += SCAT_B * 256) {   // tail
            int r = eidx[e], c = eidx[E + e];
            int p = atomicAdd(&cnt[r], 1);
            if (p < MAXDEG) slots[(size_t)r * MAXDEG + p] = c;
        }
    } else {
        // ---- node features: one wave per node, no barriers -----------------
        int wv = t >> 6, lane = t & 63;
        int i = lane & 31;
        float w[32], wg[32];
        if (lane < 32) {
#pragma unroll
            for (int k = 0; k < 32; ++k) w[k] = Wns[k * 64 + i];
        } else {
#pragma unroll
            for (int k = 0; k < 32; ++k) { w[k] = Wnv[k * 32 + i]; wg[k] = Wns[k * 64 + 32 + i]; }
        }
        float* xw = xs + wv * 128;
        const float4* xw4 = (const float4*)xw;
        const float2* x2 = (const float2*)x;
        int wid = (blockIdx.x - SCAT_B) * 4 + wv;
        const int stride = FEAT_B * 4;

        int n = wid;
        float2 cur = make_float2(0.f, 0.f);
        if (n < N) cur = x2[(size_t)n * 64 + lane];
        while (n < N) {
            int n2 = n + stride;                      // prefetch next node row
            float2 nxt = make_float2(0.f, 0.f);
            if (n2 < N) nxt = x2[(size_t)n2 * 64 + lane];
            ((float2*)xw)[lane] = cur;                // wave-private stage

            float outS = 0.f, o0 = 0.f, o1 = 0.f, o2 = 0.f;
            if (lane < 32) {
                float h = 0.f;
#pragma unroll
                for (int j = 0; j < 8; ++j) {         // s-block, b128 broadcast
                    float4 q = xw4[j];
                    h += q.x * w[4*j] + q.y * w[4*j+1] + q.z * w[4*j+2] + q.w * w[4*j+3];
                }
                outS = fmaxf(h * INV_SQRT_MUL, 0.f);
            } else {
                float gs = 0.f;
#pragma unroll
                for (int j = 0; j < 8; ++j) {         // gate over s-block
                    float4 q = xw4[j];
                    gs += q.x * wg[4*j] + q.y * wg[4*j+1] + q.z * wg[4*j+2] + q.w * wg[4*j+3];
                }
#pragma unroll
                for (int j = 0; j < 24; ++j) {        // whole v-block, full density
                    float4 q = xw4[8 + j];
                    float vals[4] = {q.x, q.y, q.z, q.w};
#pragma unroll
                    for (int m = 0; m < 4; ++m) {
                        int e = 4 * j + m;            // v elem e = 3k+d (compile-time)
                        int k = e / 3, d = e % 3;
                        float f = vals[m] * w[k];
                        if (d == 0) o0 += f; else if (d == 1) o1 += f; else o2 += f;
                    }
                }
                float sig = 1.f / (1.f + expf(-gs * INV_SQRT_MUL));
                float sc = INV_SQRT_MUL * sig;
                o0 *= sc; o1 *= sc; o2 *= sc;
            }
            float scv = __shfl(outS, i);              // hv lane grabs sc_i
            if (lane >= 32) {
                ushort4 pk;
                pk.x = f2bf(scv); pk.y = f2bf(o0); pk.z = f2bf(o1); pk.w = f2bf(o2);
                feat4[(size_t)n * 32 + i] = pk;       // coalesced 256B/row
            }
            cur = nxt; n = n2;
        }
    }
}

// --- agg: inline geometry, two-phase unrolled edge chunks --------------------
template <int U>
__device__ __forceinline__ void agg_chunk(const int* __restrict__ bucket, int j,
    const ushort4* __restrict__ feat4, const float* __restrict__ pos,
    int lane, float prx, float pry, float prz,
    float& D, float& S0, float& S1, float& S2,
    float& C0, float& C1, float& C2) {
    int col[U];
#pragma unroll
    for (int k = 0; k < U; ++k) col[k] = bucket[j + k];     // 4B broadcast
    float px[U], py[U], pz[U];
    ushort4 f[U];
#pragma unroll
    for (int k = 0; k < U; ++k) {                           // all loads in flight
        px[k] = pos[col[k] * 3 + 0];
        py[k] = pos[col[k] * 3 + 1];
        pz[k] = pos[col[k] * 3 + 2];
        f[k]  = feat4[(size_t)col[k] * 32 + lane];          // 8B/lane gather
    }
#pragma unroll
    for (int k = 0; k < U; ++k) {
        float rx = px[k] - prx, ry = py[k] - pry, rz = pz[k] - prz;
        float inv = rsqrtf(rx * rx + ry * ry + rz * rz + 1e-12f) * SQRT3;
        float u0 = ry * inv, u1 = rz * inv, u2 = rx * inv;
        float sj = bf2f(f[k].x);
        float h0 = bf2f(f[k].y), h1 = bf2f(f[k].z), h2 = bf2f(f[k].w);
        D  += h0 * u0 + h1 * u1 + h2 * u2;
        S0 += sj * u0; S1 += sj * u1; S2 += sj * u2;
        C0 += h1 * u2 - h2 * u1;
        C1 += h2 * u0 - h0 * u2;
        C2 += h0 * u1 - h1 * u0;
    }
}

__global__ __launch_bounds__(256)
void agg(const float* __restrict__ x, const float* __restrict__ pos,
         const ushort4* __restrict__ feat4, const int* __restrict__ cnt,
         const int* __restrict__ slots, const float* __restrict__ Wall,
         const float* __restrict__ gamma, const float* __restrict__ beta,
         float* __restrict__ out, int N) {
    int t = threadIdx.x;
    __shared__ float wlds[3072];
    __shared__ float4 finA[8][32];
    __shared__ float4 finB[8][32];
    {
        float4* w4 = (float4*)wlds;
        const float4* g4 = (const float4*)Wall;
        for (int i2 = t; i2 < 768; i2 += 256) w4[i2] = g4[i2];
    }
    int hw = t >> 5, lane = t & 31;
    int n = blockIdx.x * 8 + hw;
    bool live = (n < N);
    int nn = live ? n : 0;
    int deg = live ? cnt[n] : 0;
    int c = min(deg, MAXDEG);
    const int* bucket = slots + (size_t)nn * MAXDEG;
    float prx = pos[nn * 3 + 0], pry = pos[nn * 3 + 1], prz = pos[nn * 3 + 2];

    float D = 0.f, S0 = 0.f, S1 = 0.f, S2 = 0.f, C0 = 0.f, C1 = 0.f, C2 = 0.f;
    int j = 0;
    for (; j + 8 <= c; j += 8)
        agg_chunk<8>(bucket, j, feat4, pos, lane, prx, pry, prz, D, S0, S1, S2, C0, C1, C2);
    if (j + 4 <= c) {
        agg_chunk<4>(bucket, j, feat4, pos, lane, prx, pry, prz, D, S0, S1, S2, C0, C1, C2);
        j += 4;
    }
    for (; j < c; ++j)
        agg_chunk<1>(bucket, j, feat4, pos, lane, prx, pry, prz, D, S0, S1, S2, C0, C1, C2);

    finA[hw][lane] = make_float4(D, S0, S1, S2);
    finB[hw][lane] = make_float4(C0, C1, C2, 0.f);
    __syncthreads();   // covers wlds staging + fin writes

    float invdeg = 1.0f / (float)((deg > 0) ? deg : 1);
    float a0 = 0.f, aV0 = 0.f, aV1 = 0.f, aV2 = 0.f;
#pragma unroll 8
    for (int i = 0; i < 32; ++i) {
        float4 a = finA[hw][i];          // broadcast within half-wave
        float4 b = finB[hw][i];
        float wd = wlds[i * 32 + lane];
        float ws = wlds[1024 + i * 32 + lane];
        float wc = wlds[2048 + i * 32 + lane];
        a0  += a.x * wd;
        aV0 += a.y * ws + b.x * wc;
        aV1 += a.z * ws + b.y * wc;
        aV2 += a.w * ws + b.z * wc;
    }
    float vd = a0 * invdeg;
    float v0 = aV0 * invdeg, v1 = aV1 * invdeg, v2 = aV2 * invdeg;

    float s1 = vd + v0 + v1 + v2;
    float s2 = vd * vd + v0 * v0 + v1 * v1 + v2 * v2;
#pragma unroll
    for (int m = 16; m >= 1; m >>= 1) {
        s1 += __shfl_xor(s1, m);
        s2 += __shfl_xor(s2, m);
    }
    float mu = s1 * (1.f / 128.f);
    float var = s2 * (1.f / 128.f) - mu * mu;
    float rstd = rsqrtf(var + 1e-5f);

    if (live) {
        size_t base = (size_t)n * 128;
        int chv = 32 + lane * 3;
        float xv0 = __builtin_nontemporal_load(&x[base + lane]);
        float xa  = __builtin_nontemporal_load(&x[base + chv + 0]);
        float xb  = __builtin_nontemporal_load(&x[base + chv + 1]);
        float xc  = __builtin_nontemporal_load(&x[base + chv + 2]);
        __builtin_nontemporal_store(xv0 + (vd - mu) * rstd * gamma[lane] + beta[lane], &out[base + lane]);
        __builtin_nontemporal_store(xa + (v0 - mu) * rstd * gamma[chv + 0] + beta[chv + 0], &out[base + chv + 0]);
        __builtin_nontemporal_store(xb + (v1 - mu) * rstd * gamma[chv + 1] + beta[chv + 1], &out[base + chv + 1]);
        __builtin_nontemporal_store(xc + (v2 - mu) * rstd * gamma[chv + 2] + beta[chv + 2], &out[base + chv + 2]);
    }
}

// ---------------------------------------------------------------------------
extern "C" void kernel_launch(void* const* d_in, const int* in_sizes, int n_in,
                              void* d_out, int out_size, void* d_ws, size_t ws_size,
                              hipStream_t stream) {
    const float* x     = (const float*)d_in[0];
    const float* pos   = (const float*)d_in[1];
    const int*   eidx  = (const int*)d_in[2];
    const float* Wns   = (const float*)d_in[3];
    const float* Wnv   = (const float*)d_in[4];
    const float* Wtpd  = (const float*)d_in[5];
    const float* Wtps  = (const float*)d_in[6];
    const float* Wtpc  = (const float*)d_in[7];
    const float* Wms   = (const float*)d_in[8];
    const float* Wmv   = (const float*)d_in[9];
    const float* gamma = (const float*)d_in[10];
    const float* beta  = (const float*)d_in[11];
    float* out = (float*)d_out;

    int N = in_sizes[0] / 128;
    int E = in_sizes[2] / 2;

    char* ws = (char*)d_ws;
    size_t off = 0;
    unsigned short* feat = (unsigned short*)(ws + off); off += WS_ALIGN((size_t)N * 128 * 2);
    int*   cnt  = (int*)(ws + off);   off += WS_ALIGN((size_t)N * 4);
    float* Wall = (float*)(ws + off); off += WS_ALIGN(3072 * 4);
    int*   slots = (int*)(ws + off);  // N * MAXDEG * 4B (thin)

    int zb = 1 + (N + 1023) / 1024;
    fuse_zero<<<zb, 1024, 0, stream>>>(Wtpd, Wtps, Wtpc, Wms, Wmv, Wall, cnt, N);
    phase1<<<SCAT_B + FEAT_B, 256, 0, stream>>>(x, Wns, Wnv, eidx, (ushort4*)feat, cnt, slots, N, E);
    agg<<<(N + 7) / 8, 256, 0, stream>>>(x, pos, (const ushort4*)feat, cnt, slots, Wall, gamma, beta, out, N);
}

// Round 2
// 434.737 us; speedup vs baseline: 1.1004x; 1.1004x over previous
//
#include <hip/hip_runtime.h>
#include <math.h>

// ---------------------------------------------------------------------------
// EquivariantMPBlock, round 7.
//   Lesson from r6: block-role halves serialized (scatter blocks dispatched
//   first, grid 2x oversubscribed at 108 VGPR). Fix: WAVE-GRANULAR role mix -
//   every 256-thread block = 2 scatter waves + 2 feat waves, so the roles are
//   co-resident BY CONSTRUCTION at any occupancy / dispatch order.
//   feat: round-6 wave-per-node barrier-free path (b128 LDS broadcasts,
//     coalesced ushort4 stores) - unchanged, proven correct.
//   scatter: thin 4B payload (col only), 4 independent atomic chains.
//   agg: LDS-staged cu (one edge per lane computes geometry - no 32x redundant
//     u recompute), pos gathers hit L2 (pos = 1.2 MB), chunked 8/4/1 edge loop
//     for feat-gather MLP.
// ---------------------------------------------------------------------------

static constexpr float INV_SQRT_MUL = 0.17677669529663687f;   // 1/sqrt(32)
static constexpr float C_DOT = 0.10206207261596575f;          // 1/sqrt(96)
static constexpr float C_SCL = 0.07216878364870322f;          // 1/sqrt(192)
static constexpr float C_CRS = 0.05103103630798288f;          // 1/sqrt(384)
static constexpr float SQRT3 = 1.7320508075688772f;
static constexpr int MAXDEG = 48;
static constexpr int PH1_B = 1024;     // phase1 blocks; waves 0-1 scatter, 2-3 feat

#define WS_ALIGN(x) (((x) + 255) & ~(size_t)255)

__device__ __forceinline__ unsigned short f2bf(float v) {
    unsigned int b = __float_as_uint(v);
    b += 0x7FFFu + ((b >> 16) & 1u);   // RNE
    return (unsigned short)(b >> 16);
}
__device__ __forceinline__ float bf2f(unsigned short u) {
    return __uint_as_float(((unsigned int)u) << 16);
}

// --- fused + pre-scaled weights into contiguous Wall[3072]; zero cnt ---------
__global__ __launch_bounds__(1024)
void fuse_zero(const float* __restrict__ Wtpd, const float* __restrict__ Wtps,
               const float* __restrict__ Wtpc, const float* __restrict__ Wms,
               const float* __restrict__ Wmv, float* __restrict__ Wall,
               int* __restrict__ cnt, int N) {
    int t = threadIdx.x;
    if (blockIdx.x == 0) {
        int i = t >> 5, j = t & 31;
        float a = 0.f, b = 0.f, c = 0.f;
#pragma unroll
        for (int k = 0; k < 32; ++k) {
            a += Wtpd[i * 32 + k] * Wms[k * 32 + j];
            b += Wtps[i * 32 + k] * Wmv[k * 32 + j];
            c += Wtpc[i * 32 + k] * Wmv[k * 32 + j];
        }
        Wall[t]        = a * (C_DOT * INV_SQRT_MUL);
        Wall[1024 + t] = b * (C_SCL * INV_SQRT_MUL);
        Wall[2048 + t] = c * (C_CRS * INV_SQRT_MUL);
    } else {
        int i = (blockIdx.x - 1) * 1024 + t;
        if (i < N) cnt[i] = 0;
    }
}

// --- phase1: waves 0-1 scatter, waves 2-3 feat (role-mixed blocks) -----------
__global__ __launch_bounds__(256)
void phase1(const float* __restrict__ x, const float* __restrict__ Wns,
            const float* __restrict__ Wnv, const int* __restrict__ eidx,
            ushort4* __restrict__ feat4, int* __restrict__ cnt,
            int* __restrict__ slots, int N, int E) {
    __shared__ float xs[2 * 128];          // 512B per feat wave, wave-private
    int t = threadIdx.x;
    if (t < 128) {
        // ---- edge scatter: thin 4B payload, int4-vectorized, 4 MLP chains ---
        int tid = blockIdx.x * 128 + t;
        const int stride = PH1_B * 128;
        int Q = E >> 2;
        const int4* r4p = (const int4*)eidx;
        const int4* c4p = (const int4*)(eidx + E);
        for (int q = tid; q < Q; q += stride) {
            int4 R = r4p[q];
            int4 C = c4p[q];
            int rr[4] = {R.x, R.y, R.z, R.w};
            int cc[4] = {C.x, C.y, C.z, C.w};
            int p[4];
#pragma unroll
            for (int k = 0; k < 4; ++k) p[k] = atomicAdd(&cnt[rr[k]], 1);
#pragma unroll
            for (int k = 0; k < 4; ++k)
                if (p[k] < MAXDEG) slots[(size_t)rr[k] * MAXDEG + p[k]] = cc[k];
        }
        for (int e = (Q << 2) + tid; e < E; e += stride) {   // tail
            int r = eidx[e], c = eidx[E + e];
            int p = atomicAdd(&cnt[r], 1);
            if (p < MAXDEG) slots[(size_t)r * MAXDEG + p] = c;
        }
    } else {
        // ---- node features: one wave per node, no barriers -----------------
        int wv2 = (t >> 6) - 2;            // 0..1
        int lane = t & 63;
        int i = lane & 31;
        float w[32], wg[32];
        if (lane < 32) {
#pragma unroll
            for (int k = 0; k < 32; ++k) w[k] = Wns[k * 64 + i];
        } else {
#pragma unroll
            for (int k = 0; k < 32; ++k) { w[k] = Wnv[k * 32 + i]; wg[k] = Wns[k * 64 + 32 + i]; }
        }
        float* xw = xs + wv2 * 128;
        const float4* xw4 = (const float4*)xw;
        const float2* x2 = (const float2*)x;
        int wid = blockIdx.x * 2 + wv2;
        const int stride = PH1_B * 2;

        int n = wid;
        float2 cur = make_float2(0.f, 0.f);
        if (n < N) cur = x2[(size_t)n * 64 + lane];
        while (n < N) {
            int n2 = n + stride;                      // prefetch next node row
            float2 nxt = make_float2(0.f, 0.f);
            if (n2 < N) nxt = x2[(size_t)n2 * 64 + lane];
            ((float2*)xw)[lane] = cur;                // wave-private stage

            float outS = 0.f, o0 = 0.f, o1 = 0.f, o2 = 0.f;
            if (lane < 32) {
                float h = 0.f;
#pragma unroll
                for (int j = 0; j < 8; ++j) {         // s-block, b128 broadcast
                    float4 q = xw4[j];
                    h += q.x * w[4*j] + q.y * w[4*j+1] + q.z * w[4*j+2] + q.w * w[4*j+3];
                }
                outS = fmaxf(h * INV_SQRT_MUL, 0.f);
            } else {
                float gs = 0.f;
#pragma unroll
                for (int j = 0; j < 8; ++j) {         // gate over s-block
                    float4 q = xw4[j];
                    gs += q.x * wg[4*j] + q.y * wg[4*j+1] + q.z * wg[4*j+2] + q.w * wg[4*j+3];
                }
#pragma unroll
                for (int j = 0; j < 24; ++j) {        // whole v-block, full density
                    float4 q = xw4[8 + j];
                    float vals[4] = {q.x, q.y, q.z, q.w};
#pragma unroll
                    for (int m = 0; m < 4; ++m) {
                        int e = 4 * j + m;            // v elem e = 3k+d (compile-time)
                        int k = e / 3, d = e % 3;
                        float f = vals[m] * w[k];
                        if (d == 0) o0 += f; else if (d == 1) o1 += f; else o2 += f;
                    }
                }
                float sig = 1.f / (1.f + expf(-gs * INV_SQRT_MUL));
                float sc = INV_SQRT_MUL * sig;
                o0 *= sc; o1 *= sc; o2 *= sc;
            }
            float scv = __shfl(outS, i);              // hv lane grabs sc_i
            if (lane >= 32) {
                ushort4 pk;
                pk.x = f2bf(scv); pk.y = f2bf(o0); pk.z = f2bf(o1); pk.w = f2bf(o2);
                feat4[(size_t)n * 32 + i] = pk;       // coalesced 256B/row
            }
            cur = nxt; n = n2;
        }
    }
}

// --- agg: LDS-staged cu (per-lane edge geometry), chunked feat gathers -------
template <int U>
__device__ __forceinline__ void agg_chunk(const float4* __restrict__ curow, int j,
    const ushort4* __restrict__ feat4, int lane,
    float& D, float& S0, float& S1, float& S2,
    float& C0, float& C1, float& C2) {
    float4 q[U];
    ushort4 f[U];
#pragma unroll
    for (int k = 0; k < U; ++k) q[k] = curow[j + k];        // LDS broadcast
#pragma unroll
    for (int k = 0; k < U; ++k)                             // gathers in flight
        f[k] = feat4[(size_t)__float_as_int(q[k].w) * 32 + lane];
#pragma unroll
    for (int k = 0; k < U; ++k) {
        float u0 = q[k].x, u1 = q[k].y, u2 = q[k].z;
        float sj = bf2f(f[k].x);
        float h0 = bf2f(f[k].y), h1 = bf2f(f[k].z), h2 = bf2f(f[k].w);
        D  += h0 * u0 + h1 * u1 + h2 * u2;
        S0 += sj * u0; S1 += sj * u1; S2 += sj * u2;
        C0 += h1 * u2 - h2 * u1;
        C1 += h2 * u0 - h0 * u2;
        C2 += h0 * u1 - h1 * u0;
    }
}

__global__ __launch_bounds__(256)
void agg(const float* __restrict__ x, const float* __restrict__ pos,
         const ushort4* __restrict__ feat4, const int* __restrict__ cnt,
         const int* __restrict__ slots, const float* __restrict__ Wall,
         const float* __restrict__ gamma, const float* __restrict__ beta,
         float* __restrict__ out, int N) {
    int t = threadIdx.x;
    int hw = t >> 5, lane = t & 31;
    int n = blockIdx.x * 8 + hw;
    bool live = (n < N);
    int nn = live ? n : 0;

    __shared__ float4 cu[8][MAXDEG];
    __shared__ float4 finA[8][32];
    __shared__ float4 finB[8][32];

    int deg = live ? cnt[n] : 0;
    int c = min(deg, MAXDEG);

    float prx = pos[nn * 3 + 0], pry = pos[nn * 3 + 1], prz = pos[nn * 3 + 2];

    if (lane < c) {                        // one edge per lane: geometry once
        int col = slots[(size_t)nn * MAXDEG + lane];
        float rx = pos[col * 3 + 0] - prx, ry = pos[col * 3 + 1] - pry, rz = pos[col * 3 + 2] - prz;
        float inv = rsqrtf(rx * rx + ry * ry + rz * rz + 1e-12f) * SQRT3;
        cu[hw][lane] = make_float4(ry * inv, rz * inv, rx * inv, __int_as_float(col));
    }
    if (lane + 32 < c) {
        int col = slots[(size_t)nn * MAXDEG + 32 + lane];
        float rx = pos[col * 3 + 0] - prx, ry = pos[col * 3 + 1] - pry, rz = pos[col * 3 + 2] - prz;
        float inv = rsqrtf(rx * rx + ry * ry + rz * rz + 1e-12f) * SQRT3;
        cu[hw][32 + lane] = make_float4(ry * inv, rz * inv, rx * inv, __int_as_float(col));
    }
    __syncthreads();

    float D = 0.f, S0 = 0.f, S1 = 0.f, S2 = 0.f, C0 = 0.f, C1 = 0.f, C2 = 0.f;
    const float4* curow = cu[hw];
    int j = 0;
    for (; j + 8 <= c; j += 8) agg_chunk<8>(curow, j, feat4, lane, D, S0, S1, S2, C0, C1, C2);
    if (j + 4 <= c) { agg_chunk<4>(curow, j, feat4, lane, D, S0, S1, S2, C0, C1, C2); j += 4; }
    for (; j < c; ++j) agg_chunk<1>(curow, j, feat4, lane, D, S0, S1, S2, C0, C1, C2);

    finA[hw][lane] = make_float4(D, S0, S1, S2);
    finB[hw][lane] = make_float4(C0, C1, C2, 0.f);
    __syncthreads();

    float invdeg = 1.0f / (float)((deg > 0) ? deg : 1);
    float a0 = 0.f, aV0 = 0.f, aV1 = 0.f, aV2 = 0.f;
#pragma unroll 8
    for (int i = 0; i < 32; ++i) {
        float4 a = finA[hw][i];            // broadcast within half-wave
        float4 b = finB[hw][i];
        float wd = Wall[i * 32 + lane];    // L1-resident across block
        float ws = Wall[1024 + i * 32 + lane];
        float wc = Wall[2048 + i * 32 + lane];
        a0  += a.x * wd;
        aV0 += a.y * ws + b.x * wc;
        aV1 += a.z * ws + b.y * wc;
        aV2 += a.w * ws + b.z * wc;
    }
    float vd = a0 * invdeg;
    float v0 = aV0 * invdeg, v1 = aV1 * invdeg, v2 = aV2 * invdeg;

    float s1 = vd + v0 + v1 + v2;
    float s2 = vd * vd + v0 * v0 + v1 * v1 + v2 * v2;
#pragma unroll
    for (int m = 16; m >= 1; m >>= 1) {
        s1 += __shfl_xor(s1, m);
        s2 += __shfl_xor(s2, m);
    }
    float mu = s1 * (1.f / 128.f);
    float var = s2 * (1.f / 128.f) - mu * mu;
    float rstd = rsqrtf(var + 1e-5f);

    if (live) {
        size_t base = (size_t)n * 128;
        int chv = 32 + lane * 3;
        float xv0 = __builtin_nontemporal_load(&x[base + lane]);
        float xa  = __builtin_nontemporal_load(&x[base + chv + 0]);
        float xb  = __builtin_nontemporal_load(&x[base + chv + 1]);
        float xc  = __builtin_nontemporal_load(&x[base + chv + 2]);
        __builtin_nontemporal_store(xv0 + (vd - mu) * rstd * gamma[lane] + beta[lane], &out[base + lane]);
        __builtin_nontemporal_store(xa + (v0 - mu) * rstd * gamma[chv + 0] + beta[chv + 0], &out[base + chv + 0]);
        __builtin_nontemporal_store(xb + (v1 - mu) * rstd * gamma[chv + 1] + beta[chv + 1], &out[base + chv + 1]);
        __builtin_nontemporal_store(xc + (v2 - mu) * rstd * gamma[chv + 2] + beta[chv + 2], &out[base + chv + 2]);
    }
}

// ---------------------------------------------------------------------------
extern "C" void kernel_launch(void* const* d_in, const int* in_sizes, int n_in,
                              void* d_out, int out_size, void* d_ws, size_t ws_size,
                              hipStream_t stream) {
    const float* x     = (const float*)d_in[0];
    const float* pos   = (const float*)d_in[1];
    const int*   eidx  = (const int*)d_in[2];
    const float* Wns   = (const float*)d_in[3];
    const float* Wnv   = (const float*)d_in[4];
    const float* Wtpd  = (const float*)d_in[5];
    const float* Wtps  = (const float*)d_in[6];
    const float* Wtpc  = (const float*)d_in[7];
    const float* Wms   = (const float*)d_in[8];
    const float* Wmv   = (const float*)d_in[9];
    const float* gamma = (const float*)d_in[10];
    const float* beta  = (const float*)d_in[11];
    float* out = (float*)d_out;

    int N = in_sizes[0] / 128;
    int E = in_sizes[2] / 2;

    char* ws = (char*)d_ws;
    size_t off = 0;
    unsigned short* feat = (unsigned short*)(ws + off); off += WS_ALIGN((size_t)N * 128 * 2);
    int*   cnt  = (int*)(ws + off);   off += WS_ALIGN((size_t)N * 4);
    float* Wall = (float*)(ws + off); off += WS_ALIGN(3072 * 4);
    int*   slots = (int*)(ws + off);  // N * MAXDEG * 4B (thin)

    int zb = 1 + (N + 1023) / 1024;
    fuse_zero<<<zb, 1024, 0, stream>>>(Wtpd, Wtps, Wtpc, Wms, Wmv, Wall, cnt, N);
    phase1<<<PH1_B, 256, 0, stream>>>(x, Wns, Wnv, eidx, (ushort4*)feat, cnt, slots, N, E);
    agg<<<(N + 7) / 8, 256, 0, stream>>>(x, pos, (const ushort4*)feat, cnt, slots, Wall, gamma, beta, out, N);
}